// Round 26
// baseline (184.758 us; speedup 1.0000x reference)
//
#include <hip/hip_runtime.h>
#include <stdint.h>

#define S_LEN   2048
#define D_MODEL 1024
#define N_HEADS 16
#define D_HEAD  64
#define BATCH   4
#define GM      8192      // BATCH*S_LEN
#define GN      1024
#define GK      1024
#define NKT     16        // K-tiles of 64 per GEMM

typedef __attribute__((ext_vector_type(8)))  short short8;
typedef __attribute__((ext_vector_type(4)))  short short4v;
typedef __attribute__((ext_vector_type(4)))  float f32x4;
typedef __attribute__((ext_vector_type(16))) float f32x16;

__device__ __forceinline__ short f2bf(float f) {
  unsigned u = __builtin_bit_cast(unsigned, f);
  u += 0x7fffu + ((u >> 16) & 1u);   // RNE
  return (short)(u >> 16);
}

__device__ __forceinline__ unsigned cvt_pk_bf16(float lo, float hi) {
  unsigned r;
  asm("v_cvt_pk_bf16_f32 %0, %1, %2" : "=v"(r) : "v"(lo), "v"(hi));
  return r;
}

__device__ __forceinline__ short8 cvtf8(const float4 f0, const float4 f1) {
  unsigned u[4] = { cvt_pk_bf16(f0.x, f0.y), cvt_pk_bf16(f0.z, f0.w),
                    cvt_pk_bf16(f1.x, f1.y), cvt_pk_bf16(f1.z, f1.w) };
  return __builtin_bit_cast(short8, *(ulonglong2*)u);
}

__device__ __forceinline__ void gload_lds16(const short* g, short* lds_base) {
  __builtin_amdgcn_global_load_lds(
      (const __attribute__((address_space(1))) void*)(const void*)g,
      (__attribute__((address_space(3))) void*)(void*)lds_base, 16, 0, 0);
}

// ---------------------------------------------------------------------------
// cast_all: fp32 -> bf16, PRE-SWIZZLED (granule ^= row&7), one launch.
// y=0,1,2: activations query/keys/values [8192,1024] (grid.x = 4096)
// y=3..6:  weights Wv,Wk,Wq,Wo [1024,1024] (first 512 x-blocks; Wq x qscale)
// Converting A ONCE here removes the 8x fp32 L2 re-read inside gemm_qkv
// (768 MB L2 traffic -> 384 MB bf16), which is qkv's measured limiter.
// ---------------------------------------------------------------------------
__global__ __launch_bounds__(256)
void cast_all(const float* __restrict__ Iq, const float* __restrict__ Ik,
              const float* __restrict__ Iv,
              const float* __restrict__ W0, const float* __restrict__ W1,
              const float* __restrict__ W2, const float* __restrict__ W3,
              short* __restrict__ Oq, short* __restrict__ Ok,
              short* __restrict__ Ov,
              short* __restrict__ P0, short* __restrict__ P1,
              short* __restrict__ P2, short* __restrict__ P3, float qscale)
{
  const int y = blockIdx.y;
  const float* src; short* dst; float scl = 1.0f;
  if (y == 0)      { src = Iq; dst = Oq; }
  else if (y == 1) { src = Ik; dst = Ok; }
  else if (y == 2) { src = Iv; dst = Ov; }
  else {
    if (blockIdx.x >= 512) return;
    if (y == 3)      { src = W0; dst = P0; }
    else if (y == 4) { src = W1; dst = P1; }
    else if (y == 5) { src = W2; dst = P2; scl = qscale; }   // Wq * softmax scale
    else             { src = W3; dst = P3; }
  }
  const int gid = blockIdx.x * 256 + threadIdx.x;
  const int row = gid >> 7, gr = gid & 127;
  const int og  = (gr & ~7) | ((gr & 7) ^ (row & 7));
  const float* p = src + (size_t)row * 1024 + gr * 8;
  float4 f0 = *(const float4*)p, f1 = *(const float4*)(p + 4);
  f0.x *= scl; f0.y *= scl; f0.z *= scl; f0.w *= scl;
  f1.x *= scl; f1.y *= scl; f1.z *= scl; f1.w *= scl;
  *(short8*)(dst + (size_t)row * 1024 + og * 8) = cvtf8(f0, f1);
}

// ---------------------------------------------------------------------------
// Fused Q/K/V projection GEMM, round 26: PURE-DMA clone of the proven R23
// gemm_out (512 threads, 16 waves/CU, dbuf, single __syncthreads/K-step),
// z in grid selects input/weight/output; z==2 writes V transposed.
// Both operands bf16 pre-swizzled -> plain source granule, linear LDS dest,
// XOR on read (odd XOR count). Chunked XCD swizzle (1536 = 8*192).
// ---------------------------------------------------------------------------
__global__ __launch_bounds__(512, 4)
void gemm_qkv(const short* __restrict__ Aq, const short* __restrict__ Ak,
              const short* __restrict__ Av,
              const short* __restrict__ Bq, const short* __restrict__ Bk,
              const short* __restrict__ Bv,
              short* __restrict__ Cq, short* __restrict__ Ck,
              short* __restrict__ Cv)
{
  __shared__ short As[2 * 8192];
  __shared__ short Bs[2 * 8192];

  const int p  = blockIdx.x + (blockIdx.y << 3) + (blockIdx.z << 9);
  const int lg = (p & 7) * 192 + (p >> 3);     // 1536 = 8*192, bijective
  const int z  = lg >> 9;
  const int by = (lg >> 3) & 63;
  const int bx = lg & 7;

  const short* Ab = (z == 0) ? Aq : (z == 1) ? Ak : Av;
  const short* Bw = (z == 0) ? Bq : (z == 1) ? Bk : Bv;

  const int t = threadIdx.x;
  const int l = t & 63, w = t >> 6;            // 8 waves
  const int lo = l & 15, g = l >> 4;
  const int wr = (w >> 2) * 64;                // 2 row groups of 64
  const int wc = (w & 3) * 32;                 // 4 col groups of 32

  f32x4 acc[4][2] = {};

  auto stageAB = [&](int kt) {
#pragma unroll
    for (int i = 0; i < 2; ++i) {
      const int gid = i * 512 + t;             // 16B granule 0..1023
      const int row = gid >> 3;
      const int sg  = gid & 7;                 // PLAIN source (memory pre-swizzled)
      gload_lds16(Bw + (size_t)(bx * 128 + row) * GK + kt * 64 + sg * 8,
                  (short*)((char*)Bs + (kt & 1) * 16384 + gid * 16));
      gload_lds16(Ab + (size_t)(by * 128 + row) * GK + kt * 64 + sg * 8,
                  (short*)((char*)As + (kt & 1) * 16384 + gid * 16));
    }
  };

  stageAB(0);
  __syncthreads();

  for (int it = 0; it < NKT; ++it) {
    const int cur = it & 1;

    if (it + 1 < NKT) stageAB(it + 1);

#pragma unroll
    for (int kh = 0; kh < 2; ++kh) {
      short8 a[4], b[2];
      const int gg = ((kh * 4 + g) ^ (lo & 7)) * 8;
#pragma unroll
      for (int mi = 0; mi < 4; ++mi)
        a[mi] = *(const short8*)(&As[cur * 8192 + (wr + mi * 16 + lo) * 64 + gg]);
#pragma unroll
      for (int ni = 0; ni < 2; ++ni)
        b[ni] = *(const short8*)(&Bs[cur * 8192 + (wc + ni * 16 + lo) * 64 + gg]);
#pragma unroll
      for (int mi = 0; mi < 4; ++mi)
#pragma unroll
        for (int ni = 0; ni < 2; ++ni)
          acc[mi][ni] = __builtin_amdgcn_mfma_f32_16x16x32_bf16(a[mi], b[ni], acc[mi][ni], 0, 0, 0);
    }
    __syncthreads();
  }

  const int rbase = by * 128 + wr + g * 4;
  const int cbase = bx * 128 + wc + lo;

  if (z < 2) {
    short* C = (z == 0) ? Cq : Ck;
#pragma unroll
    for (int mi = 0; mi < 4; ++mi)
#pragma unroll
      for (int ni = 0; ni < 2; ++ni)
#pragma unroll
        for (int r = 0; r < 4; ++r)
          C[(size_t)(rbase + mi * 16 + r) * GN + cbase + ni * 16] = f2bf(acc[mi][ni][r]);
  } else {
#pragma unroll
    for (int mi = 0; mi < 4; ++mi)
#pragma unroll
      for (int ni = 0; ni < 2; ++ni) {
        short4v v = {f2bf(acc[mi][ni][0]), f2bf(acc[mi][ni][1]),
                     f2bf(acc[mi][ni][2]), f2bf(acc[mi][ni][3])};
        *(short4v*)(&Cv[(size_t)(cbase + ni * 16) * GM + rbase + mi * 16]) = v;
      }
  }
}

// ---------------------------------------------------------------------------
// Final GEMM (R23/R25, byte-identical): 512 threads, dbuf, single
// __syncthreads per K-step, plain-source staging of pre-swizzled operands.
// ---------------------------------------------------------------------------
__global__ __launch_bounds__(512, 4)
void gemm_out(const short* __restrict__ Ab, const short* __restrict__ Bw,
              float* __restrict__ C, const float* __restrict__ bias)
{
  __shared__ short As[2 * 8192];
  __shared__ short Bs[2 * 8192];

  const int p  = blockIdx.x + (blockIdx.y << 3);
  const int lg = (p & 7) * 64 + (p >> 3);
  const int by = lg >> 3;
  const int bx = lg & 7;

  const int t = threadIdx.x;
  const int l = t & 63, w = t >> 6;            // 8 waves
  const int lo = l & 15, g = l >> 4;
  const int wr = (w >> 2) * 64;                // 2 row groups of 64
  const int wc = (w & 3) * 32;                 // 4 col groups of 32

  f32x4 acc[4][2] = {};

  auto stageAB = [&](int kt) {
#pragma unroll
    for (int i = 0; i < 2; ++i) {
      const int gid = i * 512 + t;             // 16B granule 0..1023
      const int row = gid >> 3;
      const int sg  = gid & 7;                 // PLAIN source (memory pre-swizzled)
      gload_lds16(Bw + (size_t)(bx * 128 + row) * GK + kt * 64 + sg * 8,
                  (short*)((char*)Bs + (kt & 1) * 16384 + gid * 16));
      gload_lds16(Ab + (size_t)(by * 128 + row) * GK + kt * 64 + sg * 8,
                  (short*)((char*)As + (kt & 1) * 16384 + gid * 16));
    }
  };

  stageAB(0);
  __syncthreads();

  for (int it = 0; it < NKT; ++it) {
    const int cur = it & 1;

    if (it + 1 < NKT) stageAB(it + 1);

#pragma unroll
    for (int kh = 0; kh < 2; ++kh) {
      short8 a[4], b[2];
      const int gg = ((kh * 4 + g) ^ (lo & 7)) * 8;
#pragma unroll
      for (int mi = 0; mi < 4; ++mi)
        a[mi] = *(const short8*)(&As[cur * 8192 + (wr + mi * 16 + lo) * 64 + gg]);
#pragma unroll
      for (int ni = 0; ni < 2; ++ni)
        b[ni] = *(const short8*)(&Bs[cur * 8192 + (wc + ni * 16 + lo) * 64 + gg]);
#pragma unroll
      for (int mi = 0; mi < 4; ++mi)
#pragma unroll
        for (int ni = 0; ni < 2; ++ni)
          acc[mi][ni] = __builtin_amdgcn_mfma_f32_16x16x32_bf16(a[mi], b[ni], acc[mi][ni], 0, 0, 0);
    }
    __syncthreads();
  }

  const int rbase = by * 128 + wr + g * 4;
  const int cbase = bx * 128 + wc + lo;
#pragma unroll
  for (int ni = 0; ni < 2; ++ni) {
    const float bs = bias[cbase + ni * 16];
#pragma unroll
    for (int mi = 0; mi < 4; ++mi)
#pragma unroll
      for (int r = 0; r < 4; ++r)
        C[(size_t)(rbase + mi * 16 + r) * GN + cbase + ni * 16] = acc[mi][ni][r] + bs;
  }
}

// ---------------------------------------------------------------------------
// Flash attention v7 (byte-identical to R16/R22/R23/R25 — known-good):
// 512x512, tri-buffered K/V, counted-vmcnt barrier, max-free softmax,
// swapped-operand 32x32x16 MFMA, per-tile psum shfl (denominator FROZEN).
// ---------------------------------------------------------------------------
__global__ __launch_bounds__(512, 4)
void attn_fwd7(const short* __restrict__ Q, const short* __restrict__ Kp,
               const short* __restrict__ Vt, short* __restrict__ O)
{
  __shared__ __align__(16) char smem[49152];   // K tri 3x8K | V tri 3x8K

  const int bid = blockIdx.x;
  const int ol = ((bid & 7) << 6) | (bid >> 3);   // XCD-chunked swizzle (512 = 8*64)
  const int qt = ol & 7, h = (ol >> 3) & 15, n = ol >> 7;

  const int t = threadIdx.x, w = t >> 6, l = t & 63;
  const int lq = l & 31, hi = l >> 5;

  const short* qp = Q + ((size_t)(n * S_LEN + qt * 256 + w * 32 + lq)) * D_MODEL
                      + h * D_HEAD + hi * 8;
  short8 qf[4];
#pragma unroll
  for (int kc = 0; kc < 4; ++kc) qf[kc] = *(const short8*)(qp + kc * 16);

  const int srow = t >> 3;
  const int sg0  = (t & 7) ^ (srow & 7);
  const short* kstage = Kp + ((size_t)(n * S_LEN + srow)) * D_MODEL + h * D_HEAD + sg0 * 8;
  const short* vstage = Vt + ((size_t)(h * D_HEAD + srow)) * GM + (size_t)n * S_LEN + sg0 * 8;
  const int toff = t * 16;

  auto stage = [&](int it) {
    const int kvn = it * 64;
    const int b = (it % 3) * 8192;
    gload_lds16(kstage + (size_t)kvn * D_MODEL, (short*)(smem + b + toff));
    gload_lds16(vstage + kvn,                   (short*)(smem + 24576 + b + toff));
  };

  stage(0);
  stage(1);
  asm volatile("s_waitcnt vmcnt(2)\n\ts_barrier" ::: "memory");

  f32x16 oacc[2] = {};
  float lsum = 0.f;

  const int NT = S_LEN / 64;   // 32
  for (int it = 0; it < NT; ++it) {
    const char* Kc = smem + (it % 3) * 8192;
    const char* Vc = smem + 24576 + (it % 3) * 8192;

    if (it + 2 < NT) stage(it + 2);

    // ---- QK^T (swapped): S^T[k][q], q = lane&31 ----
    f32x16 s0 = {}, s1 = {};
    __builtin_amdgcn_s_setprio(1);
#pragma unroll
    for (int kc = 0; kc < 4; ++kc) {
      const int r0 = lq, r1 = 32 + lq;
      const short8 k0 = *(const short8*)(Kc + r0 * 128 + (((kc * 2 + hi) ^ (r0 & 7)) << 4));
      const short8 k1 = *(const short8*)(Kc + r1 * 128 + (((kc * 2 + hi) ^ (r1 & 7)) << 4));
      s0 = __builtin_amdgcn_mfma_f32_32x32x16_bf16(k0, qf[kc], s0, 0, 0, 0);
      s1 = __builtin_amdgcn_mfma_f32_32x32x16_bf16(k1, qf[kc], s1, 0, 0, 0);
    }
    __builtin_amdgcn_s_setprio(0);

    // ---- max-free softmax: P = exp2(s) (scale folded into Wq) ----
    float ps0 = 0.f, ps1 = 0.f, ps2 = 0.f, ps3 = 0.f;
    unsigned pk[16];
#pragma unroll
    for (int j = 0; j < 8; ++j) {
      const float p0 = __builtin_amdgcn_exp2f(s0[2 * j]);
      const float p1 = __builtin_amdgcn_exp2f(s0[2 * j + 1]);
      ps0 += p0; ps1 += p1;
      pk[j] = cvt_pk_bf16(p0, p1);
    }
#pragma unroll
    for (int j = 0; j < 8; ++j) {
      const float p0 = __builtin_amdgcn_exp2f(s1[2 * j]);
      const float p1 = __builtin_amdgcn_exp2f(s1[2 * j + 1]);
      ps2 += p0; ps3 += p1;
      pk[8 + j] = cvt_pk_bf16(p0, p1);
    }
    float psum = (ps0 + ps1) + (ps2 + ps3);
    psum += __shfl_xor(psum, 32, 64);
    lsum += psum;

    short8 pf[4];
#pragma unroll
    for (int kb = 0; kb < 2; ++kb)
#pragma unroll
      for (int ksl = 0; ksl < 2; ++ksl) {
        unsigned A0 = pk[kb * 8 + 4 * ksl];
        unsigned A1 = pk[kb * 8 + 4 * ksl + 1];
        unsigned B0 = pk[kb * 8 + 4 * ksl + 2];
        unsigned B1 = pk[kb * 8 + 4 * ksl + 3];
        asm("v_permlane32_swap_b32 %0, %1" : "+v"(A0), "+v"(B0));
        asm("v_permlane32_swap_b32 %0, %1" : "+v"(A1), "+v"(B1));
        unsigned wds[4] = {A0, A1, B0, B1};
        pf[kb * 2 + ksl] = __builtin_bit_cast(short8, *(ulonglong2*)wds);
      }

    // ---- PV (swapped): O^T[d][q] += V^T[d][k] * P^T[k][q] ----
    __builtin_amdgcn_s_setprio(1);
#pragma unroll
    for (int dc = 0; dc < 2; ++dc)
#pragma unroll
      for (int ks = 0; ks < 4; ++ks) {
        const int rv = dc * 32 + lq;
        const short8 vfr = *(const short8*)(Vc + rv * 128 + (((ks * 2 + hi) ^ (rv & 7)) << 4));
        oacc[dc] = __builtin_amdgcn_mfma_f32_32x32x16_bf16(vfr, pf[ks], oacc[dc], 0, 0, 0);
      }
    __builtin_amdgcn_s_setprio(0);

    if (it + 2 < NT)
      asm volatile("s_waitcnt vmcnt(2)\n\ts_barrier" ::: "memory");
    else
      asm volatile("s_waitcnt vmcnt(0)\n\ts_barrier" ::: "memory");
  }

  // ---- epilogue: O^T regs -> LDS transpose -> swizzled bf16 store ----
  short (*Os)[32][72] = (short (*)[32][72])&smem[0];
  const float inv = __builtin_amdgcn_rcpf(lsum);
#pragma unroll
  for (int dc = 0; dc < 2; ++dc)
#pragma unroll
    for (int g = 0; g < 4; ++g) {
      const int d = 32 * dc + 8 * g + 4 * hi;
      short4v v = {f2bf(oacc[dc][4 * g] * inv),     f2bf(oacc[dc][4 * g + 1] * inv),
                   f2bf(oacc[dc][4 * g + 2] * inv), f2bf(oacc[dc][4 * g + 3] * inv)};
      *(short4v*)(&Os[w][lq][d]) = v;
    }

  const int ql = l >> 1, half = l & 1;
  short* op = O + ((size_t)(n * S_LEN + qt * 256 + w * 32 + ql)) * D_MODEL + h * D_HEAD;
#pragma unroll
  for (int j = 0; j < 4; ++j) {
    const int pg = (half * 4 + j) ^ (ql & 7);
    *(short8*)(op + pg * 8) = *(const short8*)(&Os[w][ql][half * 32 + j * 8]);
  }
}

// ---------------------------------------------------------------------------
extern "C" void kernel_launch(void* const* d_in, const int* in_sizes, int n_in,
                              void* d_out, int out_size, void* d_ws, size_t ws_size,
                              hipStream_t stream) {
  const float* values = (const float*)d_in[0];
  const float* keys   = (const float*)d_in[1];
  const float* query  = (const float*)d_in[2];
  const float* Wv     = (const float*)d_in[3];
  const float* Wk     = (const float*)d_in[4];
  const float* Wq     = (const float*)d_in[5];
  const float* Wo     = (const float*)d_in[6];
  const float* bo     = (const float*)d_in[7];
  float* out = (float*)d_out;

  // ws (shorts): 4 weights (1M each) | qin,kin,vin (8M each) | qp,kp,vt
  // (8M each) = 52M shorts = 104 MB.  ao aliases qin (dead after gemm_qkv).
  short* wv  = (short*)d_ws;
  short* wk  = wv  + (size_t)1024 * 1024;
  short* wq  = wk  + (size_t)1024 * 1024;
  short* wo  = wq  + (size_t)1024 * 1024;
  short* qin = wo  + (size_t)1024 * 1024;
  short* kin = qin + (size_t)GM * GN;
  short* vin = kin + (size_t)GM * GN;
  short* qp  = vin + (size_t)GM * GN;
  short* kp  = qp  + (size_t)GM * GN;
  short* vt  = kp  + (size_t)GM * GN;
  short* ao  = qin;   // alias: qin dead after gemm_qkv

  const float qscale = 0.03125f * 1.44269504089f;   // (1/sqrt(1024))*log2(e)

  cast_all<<<dim3(4096, 7), dim3(256), 0, stream>>>(
      query, keys, values, Wv, Wk, Wq, Wo,
      qin, kin, vin, wv, wk, wq, wo, qscale);

  gemm_qkv<<<dim3(8, 64, 3), dim3(512), 0, stream>>>(
      qin, kin, vin, wq, wk, wv, qp, kp, vt);

  attn_fwd7<<<dim3(512), dim3(512), 0, stream>>>(qp, kp, vt, ao);

  gemm_out<<<dim3(GN / 128, GM / 128), dim3(512), 0, stream>>>(ao, wo, out, bo);
}

// Round 27
// 173.316 us; speedup vs baseline: 1.0660x; 1.0660x over previous
//
#include <hip/hip_runtime.h>
#include <stdint.h>

#define S_LEN   2048
#define D_MODEL 1024
#define N_HEADS 16
#define D_HEAD  64
#define BATCH   4
#define GM      8192      // BATCH*S_LEN
#define GN      1024
#define GK      1024
#define NKT     16        // K-tiles of 64 per GEMM

typedef __attribute__((ext_vector_type(8)))  short short8;
typedef __attribute__((ext_vector_type(4)))  short short4v;
typedef __attribute__((ext_vector_type(4)))  float f32x4;
typedef __attribute__((ext_vector_type(16))) float f32x16;

__device__ __forceinline__ short f2bf(float f) {
  unsigned u = __builtin_bit_cast(unsigned, f);
  u += 0x7fffu + ((u >> 16) & 1u);   // RNE
  return (short)(u >> 16);
}

__device__ __forceinline__ unsigned cvt_pk_bf16(float lo, float hi) {
  unsigned r;
  asm("v_cvt_pk_bf16_f32 %0, %1, %2" : "=v"(r) : "v"(lo), "v"(hi));
  return r;
}

__device__ __forceinline__ short8 cvtf8(const float4 f0, const float4 f1) {
  unsigned u[4] = { cvt_pk_bf16(f0.x, f0.y), cvt_pk_bf16(f0.z, f0.w),
                    cvt_pk_bf16(f1.x, f1.y), cvt_pk_bf16(f1.z, f1.w) };
  return __builtin_bit_cast(short8, *(ulonglong2*)u);
}

__device__ __forceinline__ void gload_lds16(const short* g, short* lds_base) {
  __builtin_amdgcn_global_load_lds(
      (const __attribute__((address_space(1))) void*)(const void*)g,
      (__attribute__((address_space(3))) void*)(void*)lds_base, 16, 0, 0);
}

// ---------------------------------------------------------------------------
// Weight pre-cast: fp32 [1024,1024] -> bf16, PRE-SWIZZLED (granule ^= row&7).
// ---------------------------------------------------------------------------
__global__ __launch_bounds__(256)
void cast_w(const float* __restrict__ W0, const float* __restrict__ W1,
            const float* __restrict__ W2, const float* __restrict__ W3,
            short* __restrict__ O0, short* __restrict__ O1,
            short* __restrict__ O2, short* __restrict__ O3)
{
  const int y = blockIdx.y;
  const float* src = (y == 0) ? W0 : (y == 1) ? W1 : (y == 2) ? W2 : W3;
  short*       dst = (y == 0) ? O0 : (y == 1) ? O1 : (y == 2) ? O2 : O3;
  const int gid = blockIdx.x * 256 + threadIdx.x;
  const int row = gid >> 7, gr = gid & 127;
  const int og  = (gr & ~7) | ((gr & 7) ^ (row & 7));
  const float* p = src + row * 1024 + gr * 8;
  short8 v = cvtf8(*(const float4*)p, *(const float4*)(p + 4));
  *(short8*)(dst + row * 1024 + og * 8) = v;
}

// ---------------------------------------------------------------------------
// Fused Q/K/V projection GEMM (R25 best): As DBUF (32KB) + Bs TRI (48KB) =
// 80KB -> 2 blocks/CU, 512 threads = 16 waves/CU. issueB(it+2);
// writeA(it+1)'s compiler wait (A(it+1), issued last iter) retires the OLDER
// B(it+1) for free; barrier = pure sync vmcnt(6) (retires nothing).
// B ~2 iters of flight, A ~1.3. Per-wave tile 64x32.
// ---------------------------------------------------------------------------
__global__ __launch_bounds__(512, 4)
void gemm_qkv(const float* __restrict__ Aq, const float* __restrict__ Ak,
              const float* __restrict__ Av,
              const short* __restrict__ Bq, const short* __restrict__ Bk,
              const short* __restrict__ Bv,
              short* __restrict__ Cq, short* __restrict__ Ck,
              short* __restrict__ Cv, float qscale)
{
  __shared__ short As[2 * 8192];   // [2][128][64] dbuf (ds_write staged) 32KB
  __shared__ short Bs[3 * 8192];   // [3][128][64] tri-buf (DMA staged)   48KB

  const int p  = blockIdx.x + (blockIdx.y << 3) + (blockIdx.z << 9);
  const int lg = (p & 7) * 192 + (p >> 3);     // 1536 = 8*192, bijective
  const int z  = lg >> 9;
  const int by = (lg >> 3) & 63;
  const int bx = lg & 7;

  const float* Af = (z == 0) ? Aq : (z == 1) ? Ak : Av;
  const short* Bw = (z == 0) ? Bq : (z == 1) ? Bk : Bv;

  const int t = threadIdx.x;
  const int l = t & 63, w = t >> 6;            // 8 waves
  const int lo = l & 15, g = l >> 4;
  const int wr = (w >> 2) * 64;                // 2 row groups of 64
  const int wc = (w & 3) * 32;                 // 4 col groups of 32

  f32x4 acc[4][2] = {};
  float4 aA[4], aB[4];                         // two A register sets

  auto issueB = [&](int kt) {
#pragma unroll
    for (int i = 0; i < 2; ++i) {
      const int gid = i * 512 + t;             // 16B granule 0..1023
      const int row = gid >> 3;
      const int sg  = gid & 7;                 // PLAIN source (memory pre-swizzled)
      gload_lds16(Bw + (size_t)(bx * 128 + row) * GK + kt * 64 + sg * 8,
                  (short*)((char*)Bs + (kt % 3) * 16384 + gid * 16));
    }
  };
  auto loadA = [&](int kt, float4 (&s)[4]) {
#pragma unroll
    for (int i = 0; i < 2; ++i) {
      const int u = i * 512 + t;               // 8-float unit 0..1023
      const int row = u >> 3, c8 = u & 7;
      const float* pa = Af + (size_t)(by * 128 + row) * GK + kt * 64 + c8 * 8;
      s[2 * i]     = *(const float4*)pa;
      s[2 * i + 1] = *(const float4*)(pa + 4);
    }
  };
  auto writeA = [&](int kt, float4 (&s)[4]) {
    const int base = (kt & 1) * 8192;
#pragma unroll
    for (int i = 0; i < 2; ++i) {
      const int u = i * 512 + t;
      const int row = u >> 3, c8 = u & 7;
      *(short8*)(&As[base + row * 64 + ((c8 ^ (row & 7)) * 8)]) = cvtf8(s[2 * i], s[2 * i + 1]);
    }
  };
  auto compute = [&](int it) {
    const int ab = (it & 1) * 8192;
    const int bb = (it % 3) * 8192;
#pragma unroll
    for (int kh = 0; kh < 2; ++kh) {
      short8 a[4], b[2];
      const int gg = ((kh * 4 + g) ^ (lo & 7)) * 8;
#pragma unroll
      for (int mi = 0; mi < 4; ++mi)
        a[mi] = *(const short8*)(&As[ab + (wr + mi * 16 + lo) * 64 + gg]);
#pragma unroll
      for (int ni = 0; ni < 2; ++ni)
        b[ni] = *(const short8*)(&Bs[bb + (wc + ni * 16 + lo) * 64 + gg]);
#pragma unroll
      for (int mi = 0; mi < 4; ++mi)
#pragma unroll
        for (int ni = 0; ni < 2; ++ni)
          acc[mi][ni] = __builtin_amdgcn_mfma_f32_16x16x32_bf16(a[mi], b[ni], acc[mi][ni], 0, 0, 0);
    }
  };

  auto halfIter = [&](int it, float4 (&ld)[4], float4 (&wrs)[4]) {
    if (it + 2 < NKT) issueB(it + 2);
    __builtin_amdgcn_sched_barrier(0);         // pin: B-DMAs before A-loads
    if (it + 2 < NKT) loadA(it + 2, ld);
    compute(it);
    if (it + 1 < NKT) writeA(it + 1, wrs);     // A-wait retires A(it+1) AND B(it+1)
    if (it + 2 < NKT)
      asm volatile("s_waitcnt vmcnt(6) lgkmcnt(0)\n\ts_barrier" ::: "memory");
    else
      asm volatile("s_waitcnt vmcnt(0) lgkmcnt(0)\n\ts_barrier" ::: "memory");
  };

  // ---- prologue ----
  loadA(0, aA);             // A(0)[4] oldest
  issueB(0);                // B(0)[2]
  issueB(1);                // B(1)[2]
  writeA(0, aA);            // waits A(0) only -> B(0),B(1) remain (4)
  loadA(1, aB);             // +4 = 8 outstanding
  asm volatile("s_waitcnt vmcnt(6) lgkmcnt(0)\n\ts_barrier" ::: "memory");  // retires B(0)

  for (int ith = 0; ith < NKT; ith += 2) {
    halfIter(ith,     aA, aB);   // even: load A(it+2)->aA, write A(it+1) from aB
    halfIter(ith + 1, aB, aA);   // odd:  load->aB, write from aA
  }

  const int rbase = by * 128 + wr + g * 4;
  const int cbase = bx * 128 + wc + lo;

  if (z < 2) {
    short* C = (z == 0) ? Cq : Ck;
    const float scale = (z == 0) ? qscale : 1.0f;
#pragma unroll
    for (int mi = 0; mi < 4; ++mi)
#pragma unroll
      for (int ni = 0; ni < 2; ++ni)
#pragma unroll
        for (int r = 0; r < 4; ++r)
          C[(size_t)(rbase + mi * 16 + r) * GN + cbase + ni * 16] = f2bf(acc[mi][ni][r] * scale);
  } else {
#pragma unroll
    for (int mi = 0; mi < 4; ++mi)
#pragma unroll
      for (int ni = 0; ni < 2; ++ni) {
        short4v v = {f2bf(acc[mi][ni][0]), f2bf(acc[mi][ni][1]),
                     f2bf(acc[mi][ni][2]), f2bf(acc[mi][ni][3])};
        *(short4v*)(&Cv[(size_t)(cbase + ni * 16) * GM + rbase + mi * 16]) = v;
      }
  }
}

// ---------------------------------------------------------------------------
// Final GEMM (R23/R25, byte-identical): 512 threads, dbuf, single
// __syncthreads per K-step, plain-source staging of pre-swizzled operands.
// ---------------------------------------------------------------------------
__global__ __launch_bounds__(512, 4)
void gemm_out(const short* __restrict__ Ab, const short* __restrict__ Bw,
              float* __restrict__ C, const float* __restrict__ bias)
{
  __shared__ short As[2 * 8192];
  __shared__ short Bs[2 * 8192];

  const int p  = blockIdx.x + (blockIdx.y << 3);
  const int lg = (p & 7) * 64 + (p >> 3);
  const int by = lg >> 3;
  const int bx = lg & 7;

  const int t = threadIdx.x;
  const int l = t & 63, w = t >> 6;            // 8 waves
  const int lo = l & 15, g = l >> 4;
  const int wr = (w >> 2) * 64;                // 2 row groups of 64
  const int wc = (w & 3) * 32;                 // 4 col groups of 32

  f32x4 acc[4][2] = {};

  auto stageAB = [&](int kt) {
#pragma unroll
    for (int i = 0; i < 2; ++i) {
      const int gid = i * 512 + t;             // 16B granule 0..1023
      const int row = gid >> 3;
      const int sg  = gid & 7;                 // PLAIN source (memory pre-swizzled)
      gload_lds16(Bw + (size_t)(bx * 128 + row) * GK + kt * 64 + sg * 8,
                  (short*)((char*)Bs + (kt & 1) * 16384 + gid * 16));
      gload_lds16(Ab + (size_t)(by * 128 + row) * GK + kt * 64 + sg * 8,
                  (short*)((char*)As + (kt & 1) * 16384 + gid * 16));
    }
  };

  stageAB(0);
  __syncthreads();

  for (int it = 0; it < NKT; ++it) {
    const int cur = it & 1;

    if (it + 1 < NKT) stageAB(it + 1);

#pragma unroll
    for (int kh = 0; kh < 2; ++kh) {
      short8 a[4], b[2];
      const int gg = ((kh * 4 + g) ^ (lo & 7)) * 8;
#pragma unroll
      for (int mi = 0; mi < 4; ++mi)
        a[mi] = *(const short8*)(&As[cur * 8192 + (wr + mi * 16 + lo) * 64 + gg]);
#pragma unroll
      for (int ni = 0; ni < 2; ++ni)
        b[ni] = *(const short8*)(&Bs[cur * 8192 + (wc + ni * 16 + lo) * 64 + gg]);
#pragma unroll
      for (int mi = 0; mi < 4; ++mi)
#pragma unroll
        for (int ni = 0; ni < 2; ++ni)
          acc[mi][ni] = __builtin_amdgcn_mfma_f32_16x16x32_bf16(a[mi], b[ni], acc[mi][ni], 0, 0, 0);
    }
    __syncthreads();
  }

  const int rbase = by * 128 + wr + g * 4;
  const int cbase = bx * 128 + wc + lo;
#pragma unroll
  for (int ni = 0; ni < 2; ++ni) {
    const float bs = bias[cbase + ni * 16];
#pragma unroll
    for (int mi = 0; mi < 4; ++mi)
#pragma unroll
      for (int r = 0; r < 4; ++r)
        C[(size_t)(rbase + mi * 16 + r) * GN + cbase + ni * 16] = acc[mi][ni][r] + bs;
  }
}

// ---------------------------------------------------------------------------
// Flash attention v7 (byte-identical to R16/R22/R23/R25 — known-good):
// 512x512, tri-buffered K/V, counted-vmcnt barrier, max-free softmax,
// swapped-operand 32x32x16 MFMA, per-tile psum shfl (denominator FROZEN).
// ---------------------------------------------------------------------------
__global__ __launch_bounds__(512, 4)
void attn_fwd7(const short* __restrict__ Q, const short* __restrict__ Kp,
               const short* __restrict__ Vt, short* __restrict__ O)
{
  __shared__ __align__(16) char smem[49152];   // K tri 3x8K | V tri 3x8K

  const int bid = blockIdx.x;
  const int ol = ((bid & 7) << 6) | (bid >> 3);   // XCD-chunked swizzle (512 = 8*64)
  const int qt = ol & 7, h = (ol >> 3) & 15, n = ol >> 7;

  const int t = threadIdx.x, w = t >> 6, l = t & 63;
  const int lq = l & 31, hi = l >> 5;

  const short* qp = Q + ((size_t)(n * S_LEN + qt * 256 + w * 32 + lq)) * D_MODEL
                      + h * D_HEAD + hi * 8;
  short8 qf[4];
#pragma unroll
  for (int kc = 0; kc < 4; ++kc) qf[kc] = *(const short8*)(qp + kc * 16);

  const int srow = t >> 3;
  const int sg0  = (t & 7) ^ (srow & 7);
  const short* kstage = Kp + ((size_t)(n * S_LEN + srow)) * D_MODEL + h * D_HEAD + sg0 * 8;
  const short* vstage = Vt + ((size_t)(h * D_HEAD + srow)) * GM + (size_t)n * S_LEN + sg0 * 8;
  const int toff = t * 16;

  auto stage = [&](int it) {
    const int kvn = it * 64;
    const int b = (it % 3) * 8192;
    gload_lds16(kstage + (size_t)kvn * D_MODEL, (short*)(smem + b + toff));
    gload_lds16(vstage + kvn,                   (short*)(smem + 24576 + b + toff));
  };

  stage(0);
  stage(1);
  asm volatile("s_waitcnt vmcnt(2)\n\ts_barrier" ::: "memory");

  f32x16 oacc[2] = {};
  float lsum = 0.f;

  const int NT = S_LEN / 64;   // 32
  for (int it = 0; it < NT; ++it) {
    const char* Kc = smem + (it % 3) * 8192;
    const char* Vc = smem + 24576 + (it % 3) * 8192;

    if (it + 2 < NT) stage(it + 2);

    // ---- QK^T (swapped): S^T[k][q], q = lane&31 ----
    f32x16 s0 = {}, s1 = {};
    __builtin_amdgcn_s_setprio(1);
#pragma unroll
    for (int kc = 0; kc < 4; ++kc) {
      const int r0 = lq, r1 = 32 + lq;
      const short8 k0 = *(const short8*)(Kc + r0 * 128 + (((kc * 2 + hi) ^ (r0 & 7)) << 4));
      const short8 k1 = *(const short8*)(Kc + r1 * 128 + (((kc * 2 + hi) ^ (r1 & 7)) << 4));
      s0 = __builtin_amdgcn_mfma_f32_32x32x16_bf16(k0, qf[kc], s0, 0, 0, 0);
      s1 = __builtin_amdgcn_mfma_f32_32x32x16_bf16(k1, qf[kc], s1, 0, 0, 0);
    }
    __builtin_amdgcn_s_setprio(0);

    // ---- max-free softmax: P = exp2(s) (scale folded into Q projection) ----
    float ps0 = 0.f, ps1 = 0.f, ps2 = 0.f, ps3 = 0.f;
    unsigned pk[16];
#pragma unroll
    for (int j = 0; j < 8; ++j) {
      const float p0 = __builtin_amdgcn_exp2f(s0[2 * j]);
      const float p1 = __builtin_amdgcn_exp2f(s0[2 * j + 1]);
      ps0 += p0; ps1 += p1;
      pk[j] = cvt_pk_bf16(p0, p1);
    }
#pragma unroll
    for (int j = 0; j < 8; ++j) {
      const float p0 = __builtin_amdgcn_exp2f(s1[2 * j]);
      const float p1 = __builtin_amdgcn_exp2f(s1[2 * j + 1]);
      ps2 += p0; ps3 += p1;
      pk[8 + j] = cvt_pk_bf16(p0, p1);
    }
    float psum = (ps0 + ps1) + (ps2 + ps3);
    psum += __shfl_xor(psum, 32, 64);
    lsum += psum;

    short8 pf[4];
#pragma unroll
    for (int kb = 0; kb < 2; ++kb)
#pragma unroll
      for (int ksl = 0; ksl < 2; ++ksl) {
        unsigned A0 = pk[kb * 8 + 4 * ksl];
        unsigned A1 = pk[kb * 8 + 4 * ksl + 1];
        unsigned B0 = pk[kb * 8 + 4 * ksl + 2];
        unsigned B1 = pk[kb * 8 + 4 * ksl + 3];
        asm("v_permlane32_swap_b32 %0, %1" : "+v"(A0), "+v"(B0));
        asm("v_permlane32_swap_b32 %0, %1" : "+v"(A1), "+v"(B1));
        unsigned wds[4] = {A0, A1, B0, B1};
        pf[kb * 2 + ksl] = __builtin_bit_cast(short8, *(ulonglong2*)wds);
      }

    // ---- PV (swapped): O^T[d][q] += V^T[d][k] * P^T[k][q] ----
    __builtin_amdgcn_s_setprio(1);
#pragma unroll
    for (int dc = 0; dc < 2; ++dc)
#pragma unroll
      for (int ks = 0; ks < 4; ++ks) {
        const int rv = dc * 32 + lq;
        const short8 vfr = *(const short8*)(Vc + rv * 128 + (((ks * 2 + hi) ^ (rv & 7)) << 4));
        oacc[dc] = __builtin_amdgcn_mfma_f32_32x32x16_bf16(vfr, pf[ks], oacc[dc], 0, 0, 0);
      }
    __builtin_amdgcn_s_setprio(0);

    if (it + 2 < NT)
      asm volatile("s_waitcnt vmcnt(2)\n\ts_barrier" ::: "memory");
    else
      asm volatile("s_waitcnt vmcnt(0)\n\ts_barrier" ::: "memory");
  }

  // ---- epilogue: O^T regs -> LDS transpose -> swizzled bf16 store ----
  short (*Os)[32][72] = (short (*)[32][72])&smem[0];
  const float inv = __builtin_amdgcn_rcpf(lsum);
#pragma unroll
  for (int dc = 0; dc < 2; ++dc)
#pragma unroll
    for (int g = 0; g < 4; ++g) {
      const int d = 32 * dc + 8 * g + 4 * hi;
      short4v v = {f2bf(oacc[dc][4 * g] * inv),     f2bf(oacc[dc][4 * g + 1] * inv),
                   f2bf(oacc[dc][4 * g + 2] * inv), f2bf(oacc[dc][4 * g + 3] * inv)};
      *(short4v*)(&Os[w][lq][d]) = v;
    }

  const int ql = l >> 1, half = l & 1;
  short* op = O + ((size_t)(n * S_LEN + qt * 256 + w * 32 + ql)) * D_MODEL + h * D_HEAD;
#pragma unroll
  for (int j = 0; j < 4; ++j) {
    const int pg = (half * 4 + j) ^ (ql & 7);
    *(short8*)(op + pg * 8) = *(const short8*)(&Os[w][ql][half * 32 + j * 8]);
  }
}

// ---------------------------------------------------------------------------
extern "C" void kernel_launch(void* const* d_in, const int* in_sizes, int n_in,
                              void* d_out, int out_size, void* d_ws, size_t ws_size,
                              hipStream_t stream) {
  const float* values = (const float*)d_in[0];
  const float* keys   = (const float*)d_in[1];
  const float* query  = (const float*)d_in[2];
  const float* Wv     = (const float*)d_in[3];
  const float* Wk     = (const float*)d_in[4];
  const float* Wq     = (const float*)d_in[5];
  const float* Wo     = (const float*)d_in[6];
  const float* bo     = (const float*)d_in[7];
  float* out = (float*)d_out;

  short* wv = (short*)d_ws;
  short* wk = wv + (size_t)1024 * 1024;
  short* wq = wk + (size_t)1024 * 1024;
  short* wo = wq + (size_t)1024 * 1024;
  short* qp = wo + (size_t)1024 * 1024;
  short* kp = qp + (size_t)GM * GN;
  short* vt = kp + (size_t)GM * GN;
  short* ao = vt + (size_t)GM * GN;

  dim3 bb(256);
  const float qscale = 0.03125f * 1.44269504089f;   // (1/sqrt(1024))*log2(e)

  cast_w<<<dim3(512, 4), bb, 0, stream>>>(Wv, Wk, Wq, Wo, wv, wk, wq, wo);

  gemm_qkv<<<dim3(GN / 128, GM / 128, 3), dim3(512), 0, stream>>>(
      query, keys, values, wq, wk, wv, qp, kp, vt, qscale);

  attn_fwd7<<<dim3(512), dim3(512), 0, stream>>>(qp, kp, vt, ao);

  gemm_out<<<dim3(GN / 128, GM / 128), dim3(512), 0, stream>>>(ao, wo, out, bo);
}